// Round 1
// baseline (422.580 us; speedup 1.0000x reference)
//
#include <hip/hip_runtime.h>

// MLA forward: B=2, T=2048, C=1024, LAT=256, H=16, D=64, causal, SCALE=1/8
#define SCALE 0.125f

typedef __bf16 bf16x8 __attribute__((ext_vector_type(8)));
typedef short short4v __attribute__((ext_vector_type(4)));
typedef unsigned short u16x4 __attribute__((ext_vector_type(4)));
typedef float f32x4 __attribute__((ext_vector_type(4)));

__device__ __forceinline__ unsigned short f2b(float f) {
  unsigned u = __float_as_uint(f);
  u += 0x7fffu + ((u >> 16) & 1u);   // RNE; inputs here never NaN
  return (unsigned short)(u >> 16);
}

#define GLB(p) ((__attribute__((address_space(1))) void*)(void*)(p))
#define LDSP(p) ((__attribute__((address_space(3))) void*)(p))

// ---------------- cast x: fp32 -> bf16, vectorized ----------------
__global__ void cast_f32_bf16(const float* __restrict__ in, unsigned short* __restrict__ out, int n4) {
  int i = blockIdx.x * blockDim.x + threadIdx.x;
  int stride = gridDim.x * blockDim.x;
  for (; i < n4; i += stride) {
    float4 v = ((const float4*)in)[i];
    u16x4 p;
    p.x = f2b(v.x); p.y = f2b(v.y); p.z = f2b(v.z); p.w = f2b(v.w);
    ((u16x4*)out)[i] = p;
  }
}

// ---------------- transpose + cast: w[R][C] fp32 -> wT[C][R] bf16 ----------------
__global__ void transpose_cast(const float* __restrict__ w0, const float* __restrict__ w1,
                               const float* __restrict__ w2,
                               unsigned short* __restrict__ o0, unsigned short* __restrict__ o1,
                               unsigned short* __restrict__ o2, int R, int C) {
  const float* w = blockIdx.z == 0 ? w0 : (blockIdx.z == 1 ? w1 : w2);
  unsigned short* o = blockIdx.z == 0 ? o0 : (blockIdx.z == 1 ? o1 : o2);
  __shared__ float tile[32][33];
  int c0 = blockIdx.x * 32, r0 = blockIdx.y * 32;
  int tx = threadIdx.x, ty = threadIdx.y;  // 32 x 8
#pragma unroll
  for (int i = 0; i < 32; i += 8)
    tile[ty + i][tx] = w[(size_t)(r0 + ty + i) * C + c0 + tx];
  __syncthreads();
#pragma unroll
  for (int i = 0; i < 32; i += 8)
    o[(size_t)(c0 + ty + i) * R + r0 + tx] = f2b(tile[tx][ty + i]);
}

// ---------------- GEMM: C[M,N] = A[M,K] * BT[N,K]^T, bf16 MFMA ----------------
// MODE 0: bf16 out row-major. MODE 1: bf16 out, but z==2 writes V^T[b,h,d,t].
// MODE 2: fp32 out + bias.
template <int MODE>
__global__ __launch_bounds__(256) void gemm_bt(
    const unsigned short* __restrict__ A0, const unsigned short* __restrict__ A1,
    const unsigned short* __restrict__ A2,
    const unsigned short* __restrict__ B0, const unsigned short* __restrict__ B1,
    const unsigned short* __restrict__ B2,
    void* __restrict__ C0, void* __restrict__ C1, void* __restrict__ C2,
    const float* __restrict__ bias, int M, int N, int K) {
  const int z = blockIdx.z;
  const unsigned short* A = z == 0 ? A0 : (z == 1 ? A1 : A2);
  const unsigned short* BT = z == 0 ? B0 : (z == 1 ? B1 : B2);
  void* C = z == 0 ? C0 : (z == 1 ? C1 : C2);

  __shared__ unsigned short lA[128 * 32];
  __shared__ unsigned short lB[128 * 32];

  const int t = threadIdx.x;
  const int n0 = blockIdx.x * 128;
  const int m0 = blockIdx.y * 128;
  const int lane = t & 63;
  const int wid = t >> 6;
  const int wr = wid >> 1, wc = wid & 1;
  const int lo = lane & 15, g = lane >> 4;

  f32x4 acc[4][4];
#pragma unroll
  for (int i = 0; i < 4; i++)
#pragma unroll
    for (int j = 0; j < 4; j++) acc[i][j] = (f32x4){0.f, 0.f, 0.f, 0.f};

  const unsigned short* ga = A + (size_t)(m0 + (t >> 2)) * K + (t & 3) * 8;
  const unsigned short* gb = BT + (size_t)(n0 + (t >> 2)) * K + (t & 3) * 8;
  const size_t rowK64 = (size_t)64 * K;

  for (int k0 = 0; k0 < K; k0 += 32) {
    __syncthreads();
    __builtin_amdgcn_global_load_lds(GLB(ga + k0), LDSP((char*)lA + t * 16), 16, 0, 0);
    __builtin_amdgcn_global_load_lds(GLB(ga + rowK64 + k0), LDSP((char*)lA + 4096 + t * 16), 16, 0, 0);
    __builtin_amdgcn_global_load_lds(GLB(gb + k0), LDSP((char*)lB + t * 16), 16, 0, 0);
    __builtin_amdgcn_global_load_lds(GLB(gb + rowK64 + k0), LDSP((char*)lB + 4096 + t * 16), 16, 0, 0);
    __syncthreads();

    bf16x8 af[4], bfr[4];
#pragma unroll
    for (int i = 0; i < 4; i++) {
      af[i] = *(const bf16x8*)&lA[(wr * 64 + i * 16 + lo) * 32 + g * 8];
      bfr[i] = *(const bf16x8*)&lB[(wc * 64 + i * 16 + lo) * 32 + g * 8];
    }
#pragma unroll
    for (int i = 0; i < 4; i++)
#pragma unroll
      for (int j = 0; j < 4; j++)
        acc[i][j] = __builtin_amdgcn_mfma_f32_16x16x32_bf16(af[i], bfr[j], acc[i][j], 0, 0, 0);
  }

  // epilogue: C/D layout col = lane&15, row = (lane>>4)*4 + reg
  if constexpr (MODE == 2) {
    float* Cf = (float*)C;
#pragma unroll
    for (int i = 0; i < 4; i++) {
      int row0 = m0 + wr * 64 + i * 16 + g * 4;
#pragma unroll
      for (int j = 0; j < 4; j++) {
        int col = n0 + wc * 64 + j * 16 + lo;
        float bv = bias[col];
#pragma unroll
        for (int r = 0; r < 4; r++) Cf[(size_t)(row0 + r) * N + col] = acc[i][j][r] + bv;
      }
    }
  } else {
    unsigned short* Cb = (unsigned short*)C;
    if (MODE == 1 && z == 2) {
      // V^T epilogue: out[b][h*64+d][t] = V[b*2048+t][h*64+d], laid out [b*1024+col][2048]
#pragma unroll
      for (int i = 0; i < 4; i++) {
        int row0 = m0 + wr * 64 + i * 16 + g * 4;  // 4 consecutive t
        int bb = row0 >> 11, tloc = row0 & 2047;
#pragma unroll
        for (int j = 0; j < 4; j++) {
          int col = n0 + wc * 64 + j * 16 + lo;
          u16x4 pk;
#pragma unroll
          for (int r = 0; r < 4; r++) pk[r] = f2b(acc[i][j][r]);
          *(u16x4*)&Cb[((size_t)(bb * 1024) + col) * 2048 + tloc] = pk;
        }
      }
    } else {
#pragma unroll
      for (int i = 0; i < 4; i++) {
        int row0 = m0 + wr * 64 + i * 16 + g * 4;
#pragma unroll
        for (int j = 0; j < 4; j++) {
          int col = n0 + wc * 64 + j * 16 + lo;
#pragma unroll
          for (int r = 0; r < 4; r++) Cb[(size_t)(row0 + r) * N + col] = f2b(acc[i][j][r]);
        }
      }
    }
  }
}

// ---------------- flash attention, causal, swapped-QK^T ----------------
// 1 wave = one 16-row Q tile of one (b,h). S^T = mfma(K, Q): lane holds col q=lane&15,
// rows tk=(lane>>4)*4+reg -> P is exactly the B-fragment of 16x16x16 PV MFMA (k=(l>>4)*4+e).
__global__ __launch_bounds__(256) void attn_fwd(const unsigned short* __restrict__ Q,
                                                const unsigned short* __restrict__ K,
                                                const unsigned short* __restrict__ VT,
                                                unsigned short* __restrict__ Y) {
  int wid = blockIdx.x * 4 + (threadIdx.x >> 6);
  int lane = threadIdx.x & 63;
  int lo = lane & 15, g = lane >> 4;
  int qt = wid & 127, h = (wid >> 7) & 15, b = wid >> 11;
  int q0 = qt * 16;
  int qrow = b * 2048 + q0 + lo;

  const unsigned short* qp = Q + (size_t)qrow * 1024 + h * 64 + g * 8;
  bf16x8 qf0 = *(const bf16x8*)qp;
  bf16x8 qf1 = *(const bf16x8*)(qp + 32);

  f32x4 acc[4];
#pragma unroll
  for (int i = 0; i < 4; i++) acc[i] = (f32x4){0.f, 0.f, 0.f, 0.f};
  float mrun = -3.0e38f, lrun = 0.f;

  const unsigned short* kb = K + (size_t)b * 2048 * 1024 + h * 64;
  const unsigned short* vb = VT + (size_t)(b * 16 + h) * 64 * 2048;
  const int qg = q0 + lo;
  const int ntiles = qt + 1;

  for (int kt = 0; kt < ntiles; ++kt) {
    int k0 = kt * 16;
    const unsigned short* kp = kb + (size_t)(k0 + lo) * 1024 + g * 8;
    bf16x8 kf0 = *(const bf16x8*)kp;
    bf16x8 kf1 = *(const bf16x8*)(kp + 32);

    f32x4 st = (f32x4){0.f, 0.f, 0.f, 0.f};
    st = __builtin_amdgcn_mfma_f32_16x16x32_bf16(kf0, qf0, st, 0, 0, 0);
    st = __builtin_amdgcn_mfma_f32_16x16x32_bf16(kf1, qf1, st, 0, 0, 0);

    float s[4];
    float tmax = -3.0e38f;
#pragma unroll
    for (int r = 0; r < 4; r++) {
      int tk = k0 + g * 4 + r;
      s[r] = (tk <= qg) ? st[r] * SCALE : -3.0e38f;
      tmax = fmaxf(tmax, s[r]);
    }
    tmax = fmaxf(tmax, __shfl_xor(tmax, 16));
    tmax = fmaxf(tmax, __shfl_xor(tmax, 32));
    float newm = fmaxf(mrun, tmax);
    float alpha = __expf(mrun - newm);
    mrun = newm;

    float psum = 0.f;
    short4v pb;
#pragma unroll
    for (int r = 0; r < 4; r++) {
      float p = __expf(s[r] - newm);
      psum += p;
      pb[r] = (short)f2b(p);
    }
    lrun = lrun * alpha + psum;
#pragma unroll
    for (int i = 0; i < 4; i++) acc[i] *= alpha;

#pragma unroll
    for (int dt = 0; dt < 4; dt++) {
      const unsigned short* vp = vb + (size_t)(dt * 16 + lo) * 2048 + k0 + g * 4;
      short4v vf = *(const short4v*)vp;
      acc[dt] = __builtin_amdgcn_mfma_f32_16x16x16bf16_1k(vf, pb, acc[dt], 0, 0, 0);
    }
  }

  lrun += __shfl_xor(lrun, 16);
  lrun += __shfl_xor(lrun, 32);
  float inv = 1.0f / lrun;

  unsigned short* yp = Y + (size_t)qrow * 1024 + h * 64;
#pragma unroll
  for (int dt = 0; dt < 4; dt++)
#pragma unroll
    for (int r = 0; r < 4; r++) yp[dt * 16 + g * 4 + r] = f2b(acc[dt][r] * inv);
}

// ---------------- launcher ----------------
extern "C" void kernel_launch(void* const* d_in, const int* in_sizes, int n_in,
                              void* d_out, int out_size, void* d_ws, size_t ws_size,
                              hipStream_t stream) {
  const float* x = (const float*)d_in[0];
  const float* wq_lat = (const float*)d_in[1];
  const float* wk_lat = (const float*)d_in[2];
  const float* wv_lat = (const float*)d_in[3];
  const float* wq_h = (const float*)d_in[4];
  const float* wk_h = (const float*)d_in[5];
  const float* wv_h = (const float*)d_in[6];
  const float* w_proj = (const float*)d_in[7];
  const float* b_proj = (const float*)d_in[8];
  float* out = (float*)d_out;

  char* ws = (char*)d_ws;
  unsigned short* x_bf = (unsigned short*)(ws + 0);          // 4096x1024
  unsigned short* wlatT = (unsigned short*)(ws + 8388608);   // 3 x [256][1024]
  unsigned short* whT = (unsigned short*)(ws + 9961472);     // 3 x [1024][256]
  unsigned short* wpT = (unsigned short*)(ws + 11534336);    // [1024][1024]
  unsigned short* lat = (unsigned short*)(ws + 13631488);    // 3 x [4096][256]
  unsigned short* q_bf = (unsigned short*)(ws + 19922944);   // [4096][1024]
  unsigned short* k_bf = (unsigned short*)(ws + 28311552);   // [4096][1024]
  unsigned short* vT = (unsigned short*)(ws + 36700160);     // [2][16][64][2048]
  unsigned short* y_bf = (unsigned short*)(ws + 45088768);   // [4096][1024]

  cast_f32_bf16<<<1024, 256, 0, stream>>>(x, x_bf, 4194304 / 4);
  transpose_cast<<<dim3(8, 32, 3), dim3(32, 8), 0, stream>>>(
      wq_lat, wk_lat, wv_lat, wlatT, wlatT + 262144, wlatT + 524288, 1024, 256);
  transpose_cast<<<dim3(32, 8, 3), dim3(32, 8), 0, stream>>>(
      wq_h, wk_h, wv_h, whT, whT + 262144, whT + 524288, 256, 1024);
  transpose_cast<<<dim3(32, 32, 1), dim3(32, 8), 0, stream>>>(
      w_proj, w_proj, w_proj, wpT, wpT, wpT, 1024, 1024);

  // q/k/v latent: [4096,1024] x [1024,256] -> lat[z]
  gemm_bt<0><<<dim3(2, 32, 3), 256, 0, stream>>>(
      x_bf, x_bf, x_bf, wlatT, wlatT + 262144, wlatT + 524288,
      lat, lat + 1048576, lat + 2097152, nullptr, 4096, 256, 1024);
  // up-projection: [4096,256] x [256,1024] -> q_bf, k_bf, V^T
  gemm_bt<1><<<dim3(8, 32, 3), 256, 0, stream>>>(
      lat, lat + 1048576, lat + 2097152, whT, whT + 262144, whT + 524288,
      q_bf, k_bf, vT, nullptr, 4096, 1024, 256);

  attn_fwd<<<1024, 256, 0, stream>>>(q_bf, k_bf, vT, y_bf);

  // output projection + bias -> fp32 d_out
  gemm_bt<2><<<dim3(8, 32, 1), 256, 0, stream>>>(
      y_bf, y_bf, y_bf, wpT, wpT, wpT, out, out, out, b_proj, 4096, 1024, 1024);
}

// Round 2
// 217.482 us; speedup vs baseline: 1.9431x; 1.9431x over previous
//
#include <hip/hip_runtime.h>

// MLA forward: B=2, T=2048, C=1024, LAT=256, H=16, D=64, causal, SCALE=1/8
#define SCALE 0.125f
#define SL 0.18033688011112042f  // SCALE * log2(e)

typedef __bf16 bf16x8 __attribute__((ext_vector_type(8)));
typedef short short4v __attribute__((ext_vector_type(4)));
typedef unsigned short u16x4 __attribute__((ext_vector_type(4)));
typedef float f32x4 __attribute__((ext_vector_type(4)));

__device__ __forceinline__ unsigned short f2b(float f) {
  unsigned u = __float_as_uint(f);
  u += 0x7fffu + ((u >> 16) & 1u);   // RNE; inputs here never NaN
  return (unsigned short)(u >> 16);
}

#define GLB(p) ((__attribute__((address_space(1))) void*)(void*)(p))
#define LDSP(p) ((__attribute__((address_space(3))) void*)(p))

// ---------------- cast x: fp32 -> bf16, vectorized ----------------
__global__ void cast_f32_bf16(const float* __restrict__ in, unsigned short* __restrict__ out, int n4) {
  int i = blockIdx.x * blockDim.x + threadIdx.x;
  int stride = gridDim.x * blockDim.x;
  for (; i < n4; i += stride) {
    float4 v = ((const float4*)in)[i];
    u16x4 p;
    p.x = f2b(v.x); p.y = f2b(v.y); p.z = f2b(v.z); p.w = f2b(v.w);
    ((u16x4*)out)[i] = p;
  }
}

// ---------------- transpose + cast: w[R][C] fp32 -> wT[C][R] bf16 ----------------
__global__ void transpose_cast(const float* __restrict__ w0, const float* __restrict__ w1,
                               const float* __restrict__ w2,
                               unsigned short* __restrict__ o0, unsigned short* __restrict__ o1,
                               unsigned short* __restrict__ o2, int R, int C) {
  const float* w = blockIdx.z == 0 ? w0 : (blockIdx.z == 1 ? w1 : w2);
  unsigned short* o = blockIdx.z == 0 ? o0 : (blockIdx.z == 1 ? o1 : o2);
  __shared__ float tile[32][33];
  int c0 = blockIdx.x * 32, r0 = blockIdx.y * 32;
  int tx = threadIdx.x, ty = threadIdx.y;  // 32 x 8
#pragma unroll
  for (int i = 0; i < 32; i += 8)
    tile[ty + i][tx] = w[(size_t)(r0 + ty + i) * C + c0 + tx];
  __syncthreads();
#pragma unroll
  for (int i = 0; i < 32; i += 8)
    o[(size_t)(c0 + ty + i) * R + r0 + tx] = f2b(tile[tx][ty + i]);
}

// ---------------- GEMM: C[M,N] = A[M,K] * BT[N,K]^T, bf16 MFMA ----------------
template <int MODE>
__global__ __launch_bounds__(256) void gemm_bt(
    const unsigned short* __restrict__ A0, const unsigned short* __restrict__ A1,
    const unsigned short* __restrict__ A2,
    const unsigned short* __restrict__ B0, const unsigned short* __restrict__ B1,
    const unsigned short* __restrict__ B2,
    void* __restrict__ C0, void* __restrict__ C1, void* __restrict__ C2,
    const float* __restrict__ bias, int M, int N, int K) {
  const int z = blockIdx.z;
  const unsigned short* A = z == 0 ? A0 : (z == 1 ? A1 : A2);
  const unsigned short* BT = z == 0 ? B0 : (z == 1 ? B1 : B2);
  void* C = z == 0 ? C0 : (z == 1 ? C1 : C2);

  __shared__ unsigned short lA[128 * 32];
  __shared__ unsigned short lB[128 * 32];

  const int t = threadIdx.x;
  const int n0 = blockIdx.x * 128;
  const int m0 = blockIdx.y * 128;
  const int lane = t & 63;
  const int wid = t >> 6;
  const int wr = wid >> 1, wc = wid & 1;
  const int lo = lane & 15, g = lane >> 4;

  f32x4 acc[4][4];
#pragma unroll
  for (int i = 0; i < 4; i++)
#pragma unroll
    for (int j = 0; j < 4; j++) acc[i][j] = (f32x4){0.f, 0.f, 0.f, 0.f};

  const unsigned short* ga = A + (size_t)(m0 + (t >> 2)) * K + (t & 3) * 8;
  const unsigned short* gb = BT + (size_t)(n0 + (t >> 2)) * K + (t & 3) * 8;
  const size_t rowK64 = (size_t)64 * K;

  for (int k0 = 0; k0 < K; k0 += 32) {
    __syncthreads();
    __builtin_amdgcn_global_load_lds(GLB(ga + k0), LDSP((char*)lA + t * 16), 16, 0, 0);
    __builtin_amdgcn_global_load_lds(GLB(ga + rowK64 + k0), LDSP((char*)lA + 4096 + t * 16), 16, 0, 0);
    __builtin_amdgcn_global_load_lds(GLB(gb + k0), LDSP((char*)lB + t * 16), 16, 0, 0);
    __builtin_amdgcn_global_load_lds(GLB(gb + rowK64 + k0), LDSP((char*)lB + 4096 + t * 16), 16, 0, 0);
    __syncthreads();

    bf16x8 af[4], bfr[4];
#pragma unroll
    for (int i = 0; i < 4; i++) {
      af[i] = *(const bf16x8*)&lA[(wr * 64 + i * 16 + lo) * 32 + g * 8];
      bfr[i] = *(const bf16x8*)&lB[(wc * 64 + i * 16 + lo) * 32 + g * 8];
    }
#pragma unroll
    for (int i = 0; i < 4; i++)
#pragma unroll
      for (int j = 0; j < 4; j++)
        acc[i][j] = __builtin_amdgcn_mfma_f32_16x16x32_bf16(af[i], bfr[j], acc[i][j], 0, 0, 0);
  }

  if constexpr (MODE == 2) {
    float* Cf = (float*)C;
#pragma unroll
    for (int i = 0; i < 4; i++) {
      int row0 = m0 + wr * 64 + i * 16 + g * 4;
#pragma unroll
      for (int j = 0; j < 4; j++) {
        int col = n0 + wc * 64 + j * 16 + lo;
        float bv = bias[col];
#pragma unroll
        for (int r = 0; r < 4; r++) Cf[(size_t)(row0 + r) * N + col] = acc[i][j][r] + bv;
      }
    }
  } else {
    unsigned short* Cb = (unsigned short*)C;
    if (MODE == 1 && z == 2) {
      // V^T epilogue: out[b*1024 + col][t]
#pragma unroll
      for (int i = 0; i < 4; i++) {
        int row0 = m0 + wr * 64 + i * 16 + g * 4;
        int bb = row0 >> 11, tloc = row0 & 2047;
#pragma unroll
        for (int j = 0; j < 4; j++) {
          int col = n0 + wc * 64 + j * 16 + lo;
          u16x4 pk;
#pragma unroll
          for (int r = 0; r < 4; r++) pk[r] = f2b(acc[i][j][r]);
          *(u16x4*)&Cb[((size_t)(bb * 1024) + col) * 2048 + tloc] = pk;
        }
      }
    } else {
#pragma unroll
      for (int i = 0; i < 4; i++) {
        int row0 = m0 + wr * 64 + i * 16 + g * 4;
#pragma unroll
        for (int j = 0; j < 4; j++) {
          int col = n0 + wc * 64 + j * 16 + lo;
#pragma unroll
          for (int r = 0; r < 4; r++) Cb[(size_t)(row0 + r) * N + col] = f2b(acc[i][j][r]);
        }
      }
    }
  }
}

// ---------------- flash attention, causal, swapped-QK^T, KVBLK=64, QBLK=32/wave ----------------
// S^T = mfma(K, Q): lane holds q col = lane&15, kv rows = (lane>>4)*4+r per kv-frag.
// P fragment is directly the B operand of 16x16x16 PV MFMA (k = (l>>4)*4+e).
__global__ __launch_bounds__(256) void attn_fwd(const unsigned short* __restrict__ Q,
                                                const unsigned short* __restrict__ K,
                                                const unsigned short* __restrict__ VT,
                                                unsigned short* __restrict__ Y) {
  const int w = threadIdx.x >> 6;
  const int lane = threadIdx.x & 63;
  const int lo = lane & 15, g = lane >> 4;
  const int bid = blockIdx.x;
  const int pair = bid & 31;           // (b,h)
  const int j = 15 - (bid >> 5);       // heavy chunks launch first
  const int b = pair >> 4, h = pair & 15;
  const int q0 = j * 128 + w * 32;     // this wave's 32 q rows

  const unsigned short* Qb = Q + (size_t)(b * 2048) * 1024 + h * 64;
  const unsigned short* Kb = K + (size_t)(b * 2048) * 1024 + h * 64;
  const unsigned short* Vb = VT + (size_t)((b * 16 + h) * 64) * 2048;

  // Q fragments: [qfi][dsplit]
  bf16x8 qf[2][2];
#pragma unroll
  for (int qfi = 0; qfi < 2; qfi++)
#pragma unroll
    for (int sp = 0; sp < 2; sp++)
      qf[qfi][sp] = *(const bf16x8*)(Qb + (size_t)(q0 + qfi * 16 + lo) * 1024 + sp * 32 + g * 8);

  f32x4 acc[2][4];
#pragma unroll
  for (int qfi = 0; qfi < 2; qfi++)
#pragma unroll
    for (int dt = 0; dt < 4; dt++) acc[qfi][dt] = (f32x4){0.f, 0.f, 0.f, 0.f};
  float mrun[2] = {-3.0e38f, -3.0e38f};
  float lrun[2] = {0.f, 0.f};

  const int nfull = (q0 + 1) >> 6;     // tiles with no masking for any q in this wave
  const int k0b = nfull * 64;          // single boundary (masked) tile

  bf16x8 kf[4][2];
#pragma unroll
  for (int kvf = 0; kvf < 4; kvf++)
#pragma unroll
    for (int sp = 0; sp < 2; sp++)
      kf[kvf][sp] = *(const bf16x8*)(Kb + (size_t)(kvf * 16 + lo) * 1024 + sp * 32 + g * 8);

  short4v vf[4][4];  // [dt][kvf]

#define LOADV(k0)                                                                         \
  _Pragma("unroll") for (int dt = 0; dt < 4; dt++)                                        \
  _Pragma("unroll") for (int kvf = 0; kvf < 4; kvf++)                                     \
      vf[dt][kvf] = *(const short4v*)(Vb + (size_t)(dt * 16 + lo) * 2048 + (k0) + kvf * 16 + g * 4);

#define QK(qfi, st)                                                                       \
  _Pragma("unroll") for (int kvf = 0; kvf < 4; kvf++) {                                   \
    st[kvf] = __builtin_amdgcn_mfma_f32_16x16x32_bf16(kf[kvf][0], qf[qfi][0],             \
                                                      (f32x4){0.f, 0.f, 0.f, 0.f}, 0, 0, 0); \
    st[kvf] = __builtin_amdgcn_mfma_f32_16x16x32_bf16(kf[kvf][1], qf[qfi][1], st[kvf], 0, 0, 0); \
  }

#define SOFTMAX_PV(qfi, st)                                                               \
  {                                                                                       \
    float tmax = -3.0e38f;                                                                \
    _Pragma("unroll") for (int kvf = 0; kvf < 4; kvf++)                                   \
    _Pragma("unroll") for (int r = 0; r < 4; r++) tmax = fmaxf(tmax, st[kvf][r]);         \
    tmax = fmaxf(tmax, __shfl_xor(tmax, 16));                                             \
    tmax = fmaxf(tmax, __shfl_xor(tmax, 32));                                             \
    float tl = tmax * SL;                                                                 \
    if (!__all(tl <= mrun[qfi] + 8.f)) {                                                  \
      float nm = fmaxf(mrun[qfi], tl);                                                    \
      float al = exp2f(mrun[qfi] - nm);                                                   \
      mrun[qfi] = nm;                                                                     \
      lrun[qfi] *= al;                                                                    \
      _Pragma("unroll") for (int dt = 0; dt < 4; dt++) acc[qfi][dt] *= al;                \
    }                                                                                     \
    float psum = 0.f;                                                                     \
    u16x4 pbs[4];                                                                         \
    _Pragma("unroll") for (int kvf = 0; kvf < 4; kvf++) {                                 \
      _Pragma("unroll") for (int r = 0; r < 4; r++) {                                     \
        float p = exp2f(__builtin_fmaf(st[kvf][r], SL, -mrun[qfi]));                      \
        psum += p;                                                                        \
        pbs[kvf][r] = f2b(p);                                                             \
      }                                                                                   \
    }                                                                                     \
    lrun[qfi] += psum;                                                                    \
    _Pragma("unroll") for (int dt = 0; dt < 4; dt++)                                      \
    _Pragma("unroll") for (int kvf = 0; kvf < 4; kvf++)                                   \
        acc[qfi][dt] = __builtin_amdgcn_mfma_f32_16x16x16bf16_1k(                         \
            vf[dt][kvf], (short4v)pbs[kvf], acc[qfi][dt], 0, 0, 0);                       \
  }

  for (int t = 0; t < nfull; ++t) {
    const int k0 = t * 64;
    LOADV(k0);
    f32x4 st0[4], st1[4];
    QK(0, st0);
    QK(1, st1);
    // prefetch next K tile (t+1 == nfull -> boundary tile; always in range)
    const int kn = k0 + 64;
#pragma unroll
    for (int kvf = 0; kvf < 4; kvf++)
#pragma unroll
      for (int sp = 0; sp < 2; sp++)
        kf[kvf][sp] = *(const bf16x8*)(Kb + (size_t)(kn + kvf * 16 + lo) * 1024 + sp * 32 + g * 8);
    SOFTMAX_PV(0, st0);
    SOFTMAX_PV(1, st1);
  }

  // boundary tile (kf already holds it)
  {
    LOADV(k0b);
    f32x4 st0[4], st1[4];
    QK(0, st0);
    QK(1, st1);
#pragma unroll
    for (int qfi = 0; qfi < 2; qfi++) {
      f32x4* st = qfi ? st1 : st0;
      int qg = q0 + qfi * 16 + lo;
#pragma unroll
      for (int kvf = 0; kvf < 4; kvf++)
#pragma unroll
        for (int r = 0; r < 4; r++) {
          int tk = k0b + kvf * 16 + g * 4 + r;
          if (tk > qg) st[kvf][r] = -3.0e38f;
        }
    }
    SOFTMAX_PV(0, st0);
    SOFTMAX_PV(1, st1);
  }

  // epilogue
#pragma unroll
  for (int qfi = 0; qfi < 2; qfi++) {
    float l = lrun[qfi];
    l += __shfl_xor(l, 16);
    l += __shfl_xor(l, 32);
    float inv = 1.0f / l;
    unsigned short* yp = Y + (size_t)(b * 2048 + q0 + qfi * 16 + lo) * 1024 + h * 64;
#pragma unroll
    for (int dt = 0; dt < 4; dt++) {
      u16x4 pk;
#pragma unroll
      for (int r = 0; r < 4; r++) pk[r] = f2b(acc[qfi][dt][r] * inv);
      *(u16x4*)&yp[dt * 16 + g * 4] = pk;
    }
  }
#undef LOADV
#undef QK
#undef SOFTMAX_PV
}

// ---------------- launcher ----------------
extern "C" void kernel_launch(void* const* d_in, const int* in_sizes, int n_in,
                              void* d_out, int out_size, void* d_ws, size_t ws_size,
                              hipStream_t stream) {
  const float* x = (const float*)d_in[0];
  const float* wq_lat = (const float*)d_in[1];
  const float* wk_lat = (const float*)d_in[2];
  const float* wv_lat = (const float*)d_in[3];
  const float* wq_h = (const float*)d_in[4];
  const float* wk_h = (const float*)d_in[5];
  const float* wv_h = (const float*)d_in[6];
  const float* w_proj = (const float*)d_in[7];
  const float* b_proj = (const float*)d_in[8];
  float* out = (float*)d_out;

  char* ws = (char*)d_ws;
  unsigned short* x_bf = (unsigned short*)(ws + 0);          // 4096x1024
  unsigned short* wlatT = (unsigned short*)(ws + 8388608);   // 3 x [256][1024]
  unsigned short* whT = (unsigned short*)(ws + 9961472);     // 3 x [1024][256]
  unsigned short* wpT = (unsigned short*)(ws + 11534336);    // [1024][1024]
  unsigned short* lat = (unsigned short*)(ws + 13631488);    // 3 x [4096][256]
  unsigned short* q_bf = (unsigned short*)(ws + 19922944);   // [4096][1024]
  unsigned short* k_bf = (unsigned short*)(ws + 28311552);   // [4096][1024]
  unsigned short* vT = (unsigned short*)(ws + 36700160);     // [2][16][64][2048]
  unsigned short* y_bf = (unsigned short*)(ws + 45088768);   // [4096][1024]

  cast_f32_bf16<<<1024, 256, 0, stream>>>(x, x_bf, 4194304 / 4);
  transpose_cast<<<dim3(8, 32, 3), dim3(32, 8), 0, stream>>>(
      wq_lat, wk_lat, wv_lat, wlatT, wlatT + 262144, wlatT + 524288, 1024, 256);
  transpose_cast<<<dim3(32, 8, 3), dim3(32, 8), 0, stream>>>(
      wq_h, wk_h, wv_h, whT, whT + 262144, whT + 524288, 256, 1024);
  transpose_cast<<<dim3(32, 32, 1), dim3(32, 8), 0, stream>>>(
      w_proj, w_proj, w_proj, wpT, wpT, wpT, 1024, 1024);

  gemm_bt<0><<<dim3(2, 32, 3), 256, 0, stream>>>(
      x_bf, x_bf, x_bf, wlatT, wlatT + 262144, wlatT + 524288,
      lat, lat + 1048576, lat + 2097152, nullptr, 4096, 256, 1024);
  gemm_bt<1><<<dim3(8, 32, 3), 256, 0, stream>>>(
      lat, lat + 1048576, lat + 2097152, whT, whT + 262144, whT + 524288,
      q_bf, k_bf, vT, nullptr, 4096, 1024, 256);

  attn_fwd<<<512, 256, 0, stream>>>(q_bf, k_bf, vT, y_bf);

  gemm_bt<2><<<dim3(8, 32, 1), 256, 0, stream>>>(
      y_bf, y_bf, y_bf, wpT, wpT, wpT, out, out, out, b_proj, 4096, 1024, 1024);
}